// Round 4
// baseline (236.664 us; speedup 1.0000x reference)
//
#include <hip/hip_runtime.h>
#include <math.h>

// ---- static problem geometry ----
#define NB0 1200              // scale0 obj cells / 4096  (64*3*160*160 / 4096)
#define NB1 300
#define NB2 75
#define NOBJ (NB0 + NB1 + NB2)   // 1575 dense-obj blocks
#define NPAIR 192                // 3 scales * 64 batch samples
#define NTGT (NPAIR / 8)         // 24 target blocks, 8 (s,b) pairs each
#define NFLAG (NOBJ + NTGT)      // 1599 producer blocks / flags
#define NGRID (NFLAG + 1)        // + 1 finalize block
#define CELLS0 4915200.0
#define CELLS1 1228800.0
#define CELLS2 307200.0

#define SENT 0x5A1EC0DEu         // != 0xAAAAAAAA poison, != 0

struct TgtPart { double box, pos, negc, cnt; };   // 32 B, one per (s,b) pair

__device__ __forceinline__ float softplusf(float x) {
    // stable: max(x,0) + log1p(exp(-|x|)) == jax.nn.softplus
    return fmaxf(x, 0.0f) + log1pf(expf(-fabsf(x)));
}

// Single dispatch. Producer blocks publish partials then release-store a
// sentinel flag (agent scope). Block NFLAG spins (relaxed agent loads) until
// all flags are set, acquire-fences, and reduces to the scalar loss.
// No pre-initialized memory needed: any initial flag value != SENT works.
__global__ __launch_bounds__(256) void fused_kernel(
    const float* __restrict__ p0, const float* __restrict__ p1,
    const float* __restrict__ p2, const float* __restrict__ boxes,
    const float* __restrict__ anchors,
    double* __restrict__ obj_part,          // [NOBJ]
    TgtPart* __restrict__ tgt_part,         // [NPAIR]
    unsigned int* __restrict__ flags,       // [NFLAG]
    float* __restrict__ out)
{
    const int blk = blockIdx.x;
    const int tid = threadIdx.x;

    if (blk < NOBJ) {
        // ---- dense softplus(obj) partial: one 4096-float chunk ----
        int HW4, base4;
        const float4* __restrict__ p;
        if (blk < NB0)            { p = (const float4*)p0; HW4 = 6400; base4 = blk * 1024; }
        else if (blk < NB0 + NB1) { p = (const float4*)p1; HW4 = 1600; base4 = (blk - NB0) * 1024; }
        else                      { p = (const float4*)p2; HW4 = 400;  base4 = (blk - NB0 - NB1) * 1024; }

        float sum = 0.0f;
        #pragma unroll
        for (int k = 0; k < 4; ++k) {
            int i4    = base4 + k * 256 + tid;   // float4 idx within this scale's obj cells
            int plane = i4 / HW4;                // (b*3 + a)
            int off4  = i4 - plane * HW4;
            float4 v  = p[(size_t)(plane * 6 + 4) * HW4 + off4];
            sum += softplusf(v.x) + softplusf(v.y) + softplusf(v.z) + softplusf(v.w);
        }
        #pragma unroll
        for (int off = 32; off; off >>= 1) sum += __shfl_down(sum, off);
        __shared__ float wsum[4];
        if ((tid & 63) == 0) wsum[tid >> 6] = sum;
        __syncthreads();
        if (tid == 0) {
            obj_part[blk] = (double)(wsum[0] + wsum[1] + wsum[2] + wsum[3]);
            __hip_atomic_store(&flags[blk], SENT, __ATOMIC_RELEASE,
                               __HIP_MEMORY_SCOPE_AGENT);
        }
    } else if (blk < NFLAG) {
        // ---- anchor matching + targets: 8 (s,b) pairs, 32 lanes each ----
        const int g  = tid >> 5, l = tid & 31;
        const int pi = (blk - NOBJ) * 8 + g;            // 0..191, ordered s*64+b
        const int s  = pi >> 6, b = pi & 63;
        const int G  = (s == 0) ? 160 : (s == 1 ? 80 : 40);
        const float* __restrict__ pred = (s == 0) ? p0 : (s == 1 ? p1 : p2);
        const int HW = G * G;

        __shared__ int keys[8][32];

        const float4 bx = ((const float4*)boxes)[b * 32 + l];
        const float fG = (float)G;
        const float gx = bx.x * fG, gy = bx.y * fG, gw = bx.z * fG, gh = bx.w * fG;

        int best = 0; float bestm = -1.0f;
        #pragma unroll
        for (int a = 0; a < 3; ++a) {
            float aw = anchors[s * 6 + a * 2 + 0];
            float ah = anchors[s * 6 + a * 2 + 1];
            float rw = aw / gw, rh = ah / gh;
            float m = fminf(rw, 1.0f / rw) * fminf(rh, 1.0f / rh);
            if (m > bestm) { bestm = m; best = a; }     // strict > == first argmax
        }
        const int gi = (int)gx, gj = (int)gy;           // truncation (coords > 0)
        const int key = (best * G + gj) * G + gi;
        keys[g][l] = key;
        __syncthreads();

        float sq = 0.0f, posv = 0.0f, negc = 0.0f; int cnt = 0;
        bool winner = true;                              // last duplicate wins (JAX scatter)
        for (int u = l + 1; u < 32; ++u)
            if (keys[g][u] == key) winner = false;
        if (winner) {
            float aw = anchors[s * 6 + best * 2 + 0];
            float ah = anchors[s * 6 + best * 2 + 1];
            float tx = gx - (float)gi, ty = gy - (float)gj;
            float tw = logf(gw / aw + 1e-16f), th = logf(gh / ah + 1e-16f);
            size_t base = (size_t)((b * 3 + best) * 6) * (size_t)HW + (size_t)(gj * G + gi);
            float px = pred[base + (size_t)0 * HW];
            float py = pred[base + (size_t)1 * HW];
            float pw = pred[base + (size_t)2 * HW];
            float ph = pred[base + (size_t)3 * HW];
            float po = pred[base + (size_t)4 * HW];
            float dx = px - tx, dy = py - ty, dw = pw - tw, dh = ph - th;
            sq   = dx * dx + dy * dy + dw * dw + dh * dh;
            posv = softplusf(-po);
            negc = softplusf(po);    // dense pass counted this cell as negative
            cnt  = 1;
        }

        float fcnt = (float)cnt;
        #pragma unroll
        for (int off = 16; off; off >>= 1) {             // width-32: stay inside the pair
            sq   += __shfl_down(sq,   off, 32);
            posv += __shfl_down(posv, off, 32);
            negc += __shfl_down(negc, off, 32);
            fcnt += __shfl_down(fcnt, off, 32);
        }
        if (l == 0) {
            TgtPart t; t.box = sq; t.pos = posv; t.negc = negc; t.cnt = fcnt;
            tgt_part[pi] = t;
        }
        __syncthreads();
        if (tid == 0)
            __hip_atomic_store(&flags[blk], SENT, __ATOMIC_RELEASE,
                               __HIP_MEMORY_SCOPE_AGENT);
    } else {
        // ---- finalize block: spin until all producers published ----
        for (int f = tid; f < NFLAG; f += 256) {
            int guard = 0;
            while (__hip_atomic_load(&flags[f], __ATOMIC_RELAXED,
                                     __HIP_MEMORY_SCOPE_AGENT) != SENT) {
                __builtin_amdgcn_s_sleep(1);
                if (++guard > (1 << 26)) break;   // safety: never hang the device
            }
        }
        __syncthreads();
        __threadfence();   // agent acquire: invalidate caches before reading partials

        __shared__ double negtot_s[3], box_s[3], pos_s[3], negc_s[3], cnt_s[3];
        const int wave = tid >> 6, lane = tid & 63;
        if (wave < 3) {
            const int start = (wave == 0) ? 0   : (wave == 1 ? NB0       : NB0 + NB1);
            const int end   = (wave == 0) ? NB0 : (wave == 1 ? NB0 + NB1 : NOBJ);
            double sum = 0.0;
            for (int i = start + lane; i < end; i += 64) sum += obj_part[i];
            #pragma unroll
            for (int off = 32; off; off >>= 1) sum += __shfl_down(sum, off);
            if (lane == 0) negtot_s[wave] = sum;
        } else {
            double bx2[3], ps[3], ng[3], ct[3];
            #pragma unroll
            for (int q = 0; q < 3; ++q) {
                TgtPart t = tgt_part[lane + 64 * q];   // slot/64 == scale q
                bx2[q] = t.box; ps[q] = t.pos; ng[q] = t.negc; ct[q] = t.cnt;
            }
            #pragma unroll
            for (int off = 32; off; off >>= 1) {
                #pragma unroll
                for (int q = 0; q < 3; ++q) {
                    bx2[q] += __shfl_down(bx2[q], off);
                    ps[q]  += __shfl_down(ps[q],  off);
                    ng[q]  += __shfl_down(ng[q],  off);
                    ct[q]  += __shfl_down(ct[q],  off);
                }
            }
            if (lane == 0) {
                #pragma unroll
                for (int q = 0; q < 3; ++q) {
                    box_s[q] = bx2[q]; pos_s[q] = ps[q]; negc_s[q] = ng[q]; cnt_s[q] = ct[q];
                }
            }
        }
        __syncthreads();
        if (tid == 0) {
            const double cells[3] = {CELLS0, CELLS1, CELLS2};
            double lb = 0.0, lo = 0.0;
            #pragma unroll
            for (int s = 0; s < 3; ++s) {
                double npos = cnt_s[s];
                double nneg = cells[s] - npos;
                lb += box_s[s] / npos;
                lo += pos_s[s] / npos + (negtot_s[s] - negc_s[s]) / nneg;
            }
            out[0] = (float)(0.05 * lb + 1.0 * lo);
        }
    }
}

extern "C" void kernel_launch(void* const* d_in, const int* in_sizes, int n_in,
                              void* d_out, int out_size, void* d_ws, size_t ws_size,
                              hipStream_t stream) {
    const float* p0      = (const float*)d_in[0];
    const float* p1      = (const float*)d_in[1];
    const float* p2      = (const float*)d_in[2];
    const float* boxes   = (const float*)d_in[3];
    // d_in[4] = labels (unused, nc==1)
    const float* anchors = (const float*)d_in[5];

    char* ws = (char*)d_ws;
    double*       obj_part = (double*)ws;                                   // NOBJ
    TgtPart*      tgt_part = (TgtPart*)(ws + NOBJ * sizeof(double));        // NPAIR
    unsigned int* flags    = (unsigned int*)(ws + NOBJ * sizeof(double)
                                                + NPAIR * sizeof(TgtPart)); // NFLAG
    // every slot is written unconditionally each call -> no zero-init needed;
    // flags start as 0xAA poison (or anything != SENT on the first call)

    fused_kernel<<<NGRID, 256, 0, stream>>>(p0, p1, p2, boxes, anchors,
                                            obj_part, tgt_part, flags,
                                            (float*)d_out);
}

// Round 5
// 209.117 us; speedup vs baseline: 1.1317x; 1.1317x over previous
//
#include <hip/hip_runtime.h>
#include <math.h>

// ---- static problem geometry ----
// obj cells (floats): s0 = 64*3*160*160 = 4915200, s1 = 1228800, s2 = 307200
// as float4: 1228800 / 307200 / 76800.  5120 f4 per block (20/thread):
#define OB0 240
#define OB1 60
#define OB2 15
#define NOBJB (OB0 + OB1 + OB2)     // 315 obj blocks
#define NPAIR 192                   // 3 scales * 64 batch samples
#define NTGT (NPAIR / 8)            // 24 target blocks (8 pairs * 32 lanes)
#define NGRID (NOBJB + NTGT + 1)    // + 1 consumer block = 340
#define NSLOT (NOBJB + NPAIR * 4)   // 315 obj partials + 192*4 tgt fields = 1083
#define CELLS0 4915200.0
#define CELLS1 1228800.0
#define CELLS2 307200.0

__device__ __forceinline__ float softplusf(float x) {
    // stable: max(x,0) + log1p(exp(-|x|)) == jax.nn.softplus
    return fmaxf(x, 0.0f) + log1pf(expf(-fabsf(x)));
}

// Publish: relaxed agent-scope atomic store -> write-through to coherence
// point. NO release fence => no buffer_wbl2 L2 writeback walk (R4's +65us).
__device__ __forceinline__ void publish(double* p, double v) {
    __hip_atomic_store((unsigned long long*)p, (unsigned long long)__double_as_longlong(v),
                       __ATOMIC_RELAXED, __HIP_MEMORY_SCOPE_AGENT);
}

// Spin until slot holds a valid partial. All genuine partials are strictly
// positive doubles (sign bit 0, nonzero); both init states fail the test:
// 0xAA.. poison -> sign bit 1; zero fill -> u == 0. Data IS the flag, so a
// single-address protocol needs no cross-address ordering at all.
__device__ __forceinline__ double spin_load(const double* p) {
    unsigned long long u; int guard = 0;
    for (;;) {
        u = __hip_atomic_load((const unsigned long long*)p, __ATOMIC_RELAXED,
                              __HIP_MEMORY_SCOPE_AGENT);
        if (u != 0ull && !(u >> 63)) break;     // positive nonzero double
        if (++guard > (1 << 26)) break;         // safety: never hang the device
        __builtin_amdgcn_s_sleep(1);
    }
    return __longlong_as_double(u);
}

template<int HW4>
__device__ __forceinline__ float obj_sum(const float4* __restrict__ p,
                                         int start_f4, int tid) {
    float s = 0.0f;
    #pragma unroll
    for (int k = 0; k < 20; ++k) {
        int i4    = start_f4 + k * 256 + tid;   // f4 idx within scale's obj cells
        int plane = i4 / HW4;                   // (b*3 + a); HW4 is compile-time
        int off4  = i4 - plane * HW4;
        float4 v  = p[(size_t)(plane * 6 + 4) * HW4 + off4];
        s += softplusf(v.x) + softplusf(v.y) + softplusf(v.z) + softplusf(v.w);
    }
    return s;
}

// Single dispatch. Blocks [0,315): dense softplus(obj) partials (5120 f4 each).
// Blocks [315,339): anchor match + targets, 8 (s,b) pairs per block.
// Block 339: spin-consume all 1083 slots, reduce, write scalar loss.
__global__ __launch_bounds__(256) void fused_kernel(
    const float* __restrict__ p0, const float* __restrict__ p1,
    const float* __restrict__ p2, const float* __restrict__ boxes,
    const float* __restrict__ anchors,
    double* __restrict__ slots,             // [NSLOT] in d_ws
    float* __restrict__ out)
{
    const int blk = blockIdx.x;
    const int tid = threadIdx.x;

    if (blk < NOBJB) {
        // ---- dense obj partial ----
        float sum;
        if (blk < OB0)
            sum = obj_sum<6400>((const float4*)p0, blk * 5120, tid);
        else if (blk < OB0 + OB1)
            sum = obj_sum<1600>((const float4*)p1, (blk - OB0) * 5120, tid);
        else
            sum = obj_sum<400>((const float4*)p2, (blk - OB0 - OB1) * 5120, tid);

        #pragma unroll
        for (int off = 32; off; off >>= 1) sum += __shfl_down(sum, off);
        __shared__ float wsum[4];
        if ((tid & 63) == 0) wsum[tid >> 6] = sum;
        __syncthreads();
        if (tid == 0)
            publish(&slots[blk], (double)(wsum[0] + wsum[1] + wsum[2] + wsum[3]));
    } else if (blk < NOBJB + NTGT) {
        // ---- anchor matching + targets: 8 (s,b) pairs, 32 lanes each ----
        const int g  = tid >> 5, l = tid & 31;
        const int pi = (blk - NOBJB) * 8 + g;           // 0..191, ordered s*64+b
        const int s  = pi >> 6, b = pi & 63;
        const int G  = (s == 0) ? 160 : (s == 1 ? 80 : 40);
        const float* __restrict__ pred = (s == 0) ? p0 : (s == 1 ? p1 : p2);
        const int HW = G * G;

        __shared__ int keys[8][32];

        const float4 bx = ((const float4*)boxes)[b * 32 + l];
        const float fG = (float)G;
        const float gx = bx.x * fG, gy = bx.y * fG, gw = bx.z * fG, gh = bx.w * fG;

        int best = 0; float bestm = -1.0f;
        #pragma unroll
        for (int a = 0; a < 3; ++a) {
            float aw = anchors[s * 6 + a * 2 + 0];
            float ah = anchors[s * 6 + a * 2 + 1];
            float rw = aw / gw, rh = ah / gh;
            float m = fminf(rw, 1.0f / rw) * fminf(rh, 1.0f / rh);
            if (m > bestm) { bestm = m; best = a; }     // strict > == first argmax
        }
        const int gi = (int)gx, gj = (int)gy;           // truncation (coords > 0)
        const int key = (best * G + gj) * G + gi;
        keys[g][l] = key;
        __syncthreads();

        float sq = 0.0f, posv = 0.0f, negc = 0.0f, fcnt = 0.0f;
        bool winner = true;                              // last duplicate wins (JAX scatter)
        for (int u = l + 1; u < 32; ++u)
            if (keys[g][u] == key) winner = false;
        if (winner) {
            float aw = anchors[s * 6 + best * 2 + 0];
            float ah = anchors[s * 6 + best * 2 + 1];
            float tx = gx - (float)gi, ty = gy - (float)gj;
            float tw = logf(gw / aw + 1e-16f), th = logf(gh / ah + 1e-16f);
            size_t base = (size_t)((b * 3 + best) * 6) * (size_t)HW + (size_t)(gj * G + gi);
            float px = pred[base + (size_t)0 * HW];
            float py = pred[base + (size_t)1 * HW];
            float pw = pred[base + (size_t)2 * HW];
            float ph = pred[base + (size_t)3 * HW];
            float po = pred[base + (size_t)4 * HW];
            float dx = px - tx, dy = py - ty, dw = pw - tw, dh = ph - th;
            sq   = dx * dx + dy * dy + dw * dw + dh * dh;
            posv = softplusf(-po);
            negc = softplusf(po);    // dense pass counted this cell as negative
            fcnt = 1.0f;
        }

        #pragma unroll
        for (int off = 16; off; off >>= 1) {             // width-32: stay inside pair
            sq   += __shfl_down(sq,   off, 32);
            posv += __shfl_down(posv, off, 32);
            negc += __shfl_down(negc, off, 32);
            fcnt += __shfl_down(fcnt, off, 32);
        }
        if (l == 0) {
            double* t = &slots[NOBJB + pi * 4];
            publish(&t[0], (double)sq);                  // all strictly > 0
            publish(&t[1], (double)posv);
            publish(&t[2], (double)negc);
            publish(&t[3], (double)fcnt);                // >= 1
        }
    } else {
        // ---- consumer: spin-gather all slots into LDS, then reduce ----
        __shared__ double sd[NSLOT];
        __shared__ double res[3][5];    // per scale: negtot, box, pos, negc, cnt
        for (int i = tid; i < NSLOT; i += 256)
            sd[i] = spin_load(&slots[i]);
        __syncthreads();

        const int wave = tid >> 6, lane = tid & 63;
        if (wave < 3) {
            const int start = (wave == 0) ? 0   : (wave == 1 ? OB0 : OB0 + OB1);
            const int end   = (wave == 0) ? OB0 : (wave == 1 ? OB0 + OB1 : NOBJB);
            double nt = 0.0;
            for (int i = start + lane; i < end; i += 64) nt += sd[i];
            const double* t = &sd[NOBJB + (wave * 64 + lane) * 4];  // b == lane
            double bx = t[0], ps = t[1], ng = t[2], ct = t[3];
            #pragma unroll
            for (int off = 32; off; off >>= 1) {
                nt += __shfl_down(nt, off);
                bx += __shfl_down(bx, off);
                ps += __shfl_down(ps, off);
                ng += __shfl_down(ng, off);
                ct += __shfl_down(ct, off);
            }
            if (lane == 0) {
                res[wave][0] = nt; res[wave][1] = bx; res[wave][2] = ps;
                res[wave][3] = ng; res[wave][4] = ct;
            }
        }
        __syncthreads();
        if (tid == 0) {
            const double cells[3] = {CELLS0, CELLS1, CELLS2};
            double lb = 0.0, lo = 0.0;
            #pragma unroll
            for (int s = 0; s < 3; ++s) {
                double npos = res[s][4];
                double nneg = cells[s] - npos;
                lb += res[s][1] / npos;
                lo += res[s][2] / npos + (res[s][0] - res[s][3]) / nneg;
            }
            out[0] = (float)(0.05 * lb + 1.0 * lo);
        }
    }
}

extern "C" void kernel_launch(void* const* d_in, const int* in_sizes, int n_in,
                              void* d_out, int out_size, void* d_ws, size_t ws_size,
                              hipStream_t stream) {
    const float* p0      = (const float*)d_in[0];
    const float* p1      = (const float*)d_in[1];
    const float* p2      = (const float*)d_in[2];
    const float* boxes   = (const float*)d_in[3];
    // d_in[4] = labels (unused, nc==1)
    const float* anchors = (const float*)d_in[5];

    double* slots = (double*)d_ws;   // NSLOT doubles; any init state != valid-positive works

    fused_kernel<<<NGRID, 256, 0, stream>>>(p0, p1, p2, boxes, anchors,
                                            slots, (float*)d_out);
}

// Round 6
// 208.397 us; speedup vs baseline: 1.1356x; 1.0035x over previous
//
#include <hip/hip_runtime.h>
#include <math.h>

// ---- static problem geometry ----
// obj cells (floats): s0 = 64*3*160*160 = 4915200, s1 = 1228800, s2 = 307200
// as float4: 1228800 / 307200 / 76800.  5120 f4 per block (20/thread):
#define OB0 240
#define OB1 60
#define OB2 15
#define NOBJB (OB0 + OB1 + OB2)     // 315 obj blocks
#define NPAIR 192                   // 3 scales * 64 batch samples
#define NTGT (NPAIR / 8)            // 24 target blocks (8 pairs * 32 lanes)
#define NGRID (NOBJB + NTGT)        // 339 producer blocks
#define CELLS0 4915200.0
#define CELLS1 1228800.0
#define CELLS2 307200.0

struct TgtPart { double box, pos, negc, cnt; };   // 32 B, one per (s,b) pair

__device__ __forceinline__ float softplusf(float x) {
    // stable: max(x,0) + log1p(exp(-|x|)) == jax.nn.softplus
    return fmaxf(x, 0.0f) + log1pf(expf(-fabsf(x)));
}

template<int HW4>
__device__ __forceinline__ float obj_sum(const float4* __restrict__ p,
                                         int start_f4, int tid) {
    float s = 0.0f;
    #pragma unroll
    for (int k = 0; k < 20; ++k) {
        int i4    = start_f4 + k * 256 + tid;   // f4 idx within scale's obj cells
        int plane = i4 / HW4;                   // (b*3 + a); HW4 compile-time
        int off4  = i4 - plane * HW4;
        float4 v  = p[(size_t)(plane * 6 + 4) * HW4 + off4];
        s += softplusf(v.x) + softplusf(v.y) + softplusf(v.z) + softplusf(v.w);
    }
    return s;
}

// Dispatch 1. Blocks [0,315): dense softplus(obj) partials, 5120 float4 each,
// single-writer slot (no atomics, no init). Blocks [315,339): anchor matching
// + targets, 8 (s,b) pairs per block (32 lanes per pair).
__global__ __launch_bounds__(256) void main_kernel(
    const float* __restrict__ p0, const float* __restrict__ p1,
    const float* __restrict__ p2, const float* __restrict__ boxes,
    const float* __restrict__ anchors,
    double* __restrict__ obj_part,      // [NOBJB]
    TgtPart* __restrict__ tgt_part)     // [NPAIR]
{
    const int blk = blockIdx.x;
    const int tid = threadIdx.x;

    if (blk < NOBJB) {
        float sum;
        if (blk < OB0)
            sum = obj_sum<6400>((const float4*)p0, blk * 5120, tid);
        else if (blk < OB0 + OB1)
            sum = obj_sum<1600>((const float4*)p1, (blk - OB0) * 5120, tid);
        else
            sum = obj_sum<400>((const float4*)p2, (blk - OB0 - OB1) * 5120, tid);

        #pragma unroll
        for (int off = 32; off; off >>= 1) sum += __shfl_down(sum, off);
        __shared__ float wsum[4];
        if ((tid & 63) == 0) wsum[tid >> 6] = sum;
        __syncthreads();
        if (tid == 0)
            obj_part[blk] = (double)(wsum[0] + wsum[1] + wsum[2] + wsum[3]);
    } else {
        const int g  = tid >> 5, l = tid & 31;          // pair group, lane in pair
        const int pi = (blk - NOBJB) * 8 + g;           // 0..191, ordered s*64+b
        const int s  = pi >> 6, b = pi & 63;
        const int G  = (s == 0) ? 160 : (s == 1 ? 80 : 40);
        const float* __restrict__ pred = (s == 0) ? p0 : (s == 1 ? p1 : p2);
        const int HW = G * G;

        __shared__ int keys[8][32];

        const float4 bx = ((const float4*)boxes)[b * 32 + l];
        const float fG = (float)G;
        const float gx = bx.x * fG, gy = bx.y * fG, gw = bx.z * fG, gh = bx.w * fG;

        int best = 0; float bestm = -1.0f;
        #pragma unroll
        for (int a = 0; a < 3; ++a) {
            float aw = anchors[s * 6 + a * 2 + 0];
            float ah = anchors[s * 6 + a * 2 + 1];
            float rw = aw / gw, rh = ah / gh;
            float m = fminf(rw, 1.0f / rw) * fminf(rh, 1.0f / rh);
            if (m > bestm) { bestm = m; best = a; }     // strict > == first argmax
        }
        const int gi = (int)gx, gj = (int)gy;           // truncation (coords > 0)
        const int key = (best * G + gj) * G + gi;
        keys[g][l] = key;
        __syncthreads();

        float sq = 0.0f, posv = 0.0f, negc = 0.0f, fcnt = 0.0f;
        bool winner = true;                              // last duplicate wins (JAX scatter)
        for (int u = l + 1; u < 32; ++u)
            if (keys[g][u] == key) winner = false;
        if (winner) {
            float aw = anchors[s * 6 + best * 2 + 0];
            float ah = anchors[s * 6 + best * 2 + 1];
            float tx = gx - (float)gi, ty = gy - (float)gj;
            float tw = logf(gw / aw + 1e-16f), th = logf(gh / ah + 1e-16f);
            size_t base = (size_t)((b * 3 + best) * 6) * (size_t)HW + (size_t)(gj * G + gi);
            float px = pred[base + (size_t)0 * HW];
            float py = pred[base + (size_t)1 * HW];
            float pw = pred[base + (size_t)2 * HW];
            float ph = pred[base + (size_t)3 * HW];
            float po = pred[base + (size_t)4 * HW];
            float dx = px - tx, dy = py - ty, dw = pw - tw, dh = ph - th;
            sq   = dx * dx + dy * dy + dw * dw + dh * dh;
            posv = softplusf(-po);
            negc = softplusf(po);    // dense pass counted this cell as negative
            fcnt = 1.0f;
        }

        #pragma unroll
        for (int off = 16; off; off >>= 1) {             // width-32: stay inside pair
            sq   += __shfl_down(sq,   off, 32);
            posv += __shfl_down(posv, off, 32);
            negc += __shfl_down(negc, off, 32);
            fcnt += __shfl_down(fcnt, off, 32);
        }
        if (l == 0) {
            TgtPart t; t.box = sq; t.pos = posv; t.negc = negc; t.cnt = fcnt;
            tgt_part[pi] = t;
        }
    }
}

// Dispatch 2, one block. Waves 0-2 sum the per-scale obj partials
// (240/60/15 slots); wave 3 reduces the 192 per-pair target partials
// (pair/64 == scale by construction); lane 0 combines into the scalar loss.
__global__ __launch_bounds__(256) void finalize_kernel(
    const double* __restrict__ obj_part, const TgtPart* __restrict__ tgt_part,
    float* __restrict__ out)
{
    __shared__ double negtot_s[3], box_s[3], pos_s[3], negc_s[3], cnt_s[3];
    const int tid = threadIdx.x;
    const int wave = tid >> 6, lane = tid & 63;

    if (wave < 3) {
        const int start = (wave == 0) ? 0   : (wave == 1 ? OB0 : OB0 + OB1);
        const int end   = (wave == 0) ? OB0 : (wave == 1 ? OB0 + OB1 : NOBJB);
        double sum = 0.0;
        for (int i = start + lane; i < end; i += 64) sum += obj_part[i];
        #pragma unroll
        for (int off = 32; off; off >>= 1) sum += __shfl_down(sum, off);
        if (lane == 0) negtot_s[wave] = sum;
    } else {
        double bx[3], ps[3], ng[3], ct[3];
        #pragma unroll
        for (int q = 0; q < 3; ++q) {
            TgtPart t = tgt_part[lane + 64 * q];   // pair/64 == scale q, b == lane
            bx[q] = t.box; ps[q] = t.pos; ng[q] = t.negc; ct[q] = t.cnt;
        }
        #pragma unroll
        for (int off = 32; off; off >>= 1) {
            #pragma unroll
            for (int q = 0; q < 3; ++q) {
                bx[q] += __shfl_down(bx[q], off);
                ps[q] += __shfl_down(ps[q], off);
                ng[q] += __shfl_down(ng[q], off);
                ct[q] += __shfl_down(ct[q], off);
            }
        }
        if (lane == 0) {
            #pragma unroll
            for (int q = 0; q < 3; ++q) {
                box_s[q] = bx[q]; pos_s[q] = ps[q]; negc_s[q] = ng[q]; cnt_s[q] = ct[q];
            }
        }
    }
    __syncthreads();
    if (tid == 0) {
        const double cells[3] = {CELLS0, CELLS1, CELLS2};
        double lb = 0.0, lo = 0.0;
        #pragma unroll
        for (int s = 0; s < 3; ++s) {
            double npos = cnt_s[s];
            double nneg = cells[s] - npos;
            lb += box_s[s] / npos;
            lo += pos_s[s] / npos + (negtot_s[s] - negc_s[s]) / nneg;
        }
        out[0] = (float)(0.05 * lb + 1.0 * lo);
    }
}

extern "C" void kernel_launch(void* const* d_in, const int* in_sizes, int n_in,
                              void* d_out, int out_size, void* d_ws, size_t ws_size,
                              hipStream_t stream) {
    const float* p0      = (const float*)d_in[0];
    const float* p1      = (const float*)d_in[1];
    const float* p2      = (const float*)d_in[2];
    const float* boxes   = (const float*)d_in[3];
    // d_in[4] = labels (unused, nc==1)
    const float* anchors = (const float*)d_in[5];

    double*  obj_part = (double*)d_ws;                                    // NOBJB
    TgtPart* tgt_part = (TgtPart*)((char*)d_ws + NOBJB * sizeof(double)); // NPAIR
    // every slot written unconditionally each call -> no zero-init needed

    main_kernel<<<NGRID, 256, 0, stream>>>(p0, p1, p2, boxes, anchors,
                                           obj_part, tgt_part);
    finalize_kernel<<<1, 256, 0, stream>>>(obj_part, tgt_part, (float*)d_out);
}

// Round 7
// 191.128 us; speedup vs baseline: 1.2383x; 1.0904x over previous
//
#include <hip/hip_runtime.h>
#include <math.h>

// ---- static problem geometry ----
#define NB0 1200              // scale0 obj cells / 4096  (64*3*160*160 / 4096)
#define NB1 300
#define NB2 75
#define NOBJ (NB0 + NB1 + NB2)   // 1575 dense-obj blocks
#define NPAIR 192                // 3 scales * 64 batch samples
#define NTGT (NPAIR / 8)         // 24 target blocks, 8 (s,b) pairs each
#define CELLS0 4915200.0
#define CELLS1 1228800.0
#define CELLS2 307200.0

struct TgtPart { double box, pos, negc, cnt; };   // 32 B, one per (s,b) pair

__device__ __forceinline__ float softplusf(float x) {
    // stable: max(x,0) + log1p(exp(-|x|)) == jax.nn.softplus
    return fmaxf(x, 0.0f) + log1pf(expf(-fabsf(x)));
}

// Fused kernel. Blocks [0, NOBJ): dense softplus(obj) partial sums, one
// 4096-float chunk each, single-writer slot (no atomics, no init needed).
// Blocks [NOBJ, NOBJ+NTGT): anchor matching + targets, 8 (s,b) pairs per
// block (32 lanes per pair), one TgtPart slot per pair.
__global__ __launch_bounds__(256) void main_kernel(
    const float* __restrict__ p0, const float* __restrict__ p1,
    const float* __restrict__ p2, const float* __restrict__ boxes,
    const float* __restrict__ anchors,
    double* __restrict__ obj_part,      // [NOBJ]
    TgtPart* __restrict__ tgt_part)     // [NPAIR]
{
    const int blk = blockIdx.x;
    const int tid = threadIdx.x;

    if (blk < NOBJ) {
        int HW4, base4;
        const float4* __restrict__ p;
        if (blk < NB0)            { p = (const float4*)p0; HW4 = 6400; base4 = blk * 1024; }
        else if (blk < NB0 + NB1) { p = (const float4*)p1; HW4 = 1600; base4 = (blk - NB0) * 1024; }
        else                      { p = (const float4*)p2; HW4 = 400;  base4 = (blk - NB0 - NB1) * 1024; }

        float sum = 0.0f;
        #pragma unroll
        for (int k = 0; k < 4; ++k) {
            int i4    = base4 + k * 256 + tid;   // float4 idx within this scale's obj cells
            int plane = i4 / HW4;                // (b*3 + a)
            int off4  = i4 - plane * HW4;
            float4 v  = p[(size_t)(plane * 6 + 4) * HW4 + off4];
            sum += softplusf(v.x) + softplusf(v.y) + softplusf(v.z) + softplusf(v.w);
        }
        #pragma unroll
        for (int off = 32; off; off >>= 1) sum += __shfl_down(sum, off);
        __shared__ float wsum[4];
        if ((tid & 63) == 0) wsum[tid >> 6] = sum;
        __syncthreads();
        if (tid == 0)
            obj_part[blk] = (double)(wsum[0] + wsum[1] + wsum[2] + wsum[3]);
    } else {
        const int g  = tid >> 5, l = tid & 31;          // pair group, lane in pair
        const int pi = (blk - NOBJ) * 8 + g;            // 0..191, ordered s*64+b
        const int s  = pi >> 6, b = pi & 63;
        const int G  = (s == 0) ? 160 : (s == 1 ? 80 : 40);
        const float* __restrict__ pred = (s == 0) ? p0 : (s == 1 ? p1 : p2);
        const int HW = G * G;

        __shared__ int keys[8][32];

        const float4 bx = ((const float4*)boxes)[b * 32 + l];
        const float fG = (float)G;
        const float gx = bx.x * fG, gy = bx.y * fG, gw = bx.z * fG, gh = bx.w * fG;

        int best = 0; float bestm = -1.0f;
        #pragma unroll
        for (int a = 0; a < 3; ++a) {
            float aw = anchors[s * 6 + a * 2 + 0];
            float ah = anchors[s * 6 + a * 2 + 1];
            float rw = aw / gw, rh = ah / gh;
            float m = fminf(rw, 1.0f / rw) * fminf(rh, 1.0f / rh);
            if (m > bestm) { bestm = m; best = a; }     // strict > == first argmax
        }
        const int gi = (int)gx, gj = (int)gy;           // truncation (coords > 0)
        const int key = (best * G + gj) * G + gi;
        keys[g][l] = key;
        __syncthreads();

        float sq = 0.0f, posv = 0.0f, negc = 0.0f; int cnt = 0;
        bool winner = true;                              // last duplicate wins (JAX scatter)
        for (int u = l + 1; u < 32; ++u)
            if (keys[g][u] == key) winner = false;
        if (winner) {
            float aw = anchors[s * 6 + best * 2 + 0];
            float ah = anchors[s * 6 + best * 2 + 1];
            float tx = gx - (float)gi, ty = gy - (float)gj;
            float tw = logf(gw / aw + 1e-16f), th = logf(gh / ah + 1e-16f);
            size_t base = (size_t)((b * 3 + best) * 6) * (size_t)HW + (size_t)(gj * G + gi);
            float px = pred[base + (size_t)0 * HW];
            float py = pred[base + (size_t)1 * HW];
            float pw = pred[base + (size_t)2 * HW];
            float ph = pred[base + (size_t)3 * HW];
            float po = pred[base + (size_t)4 * HW];
            float dx = px - tx, dy = py - ty, dw = pw - tw, dh = ph - th;
            sq   = dx * dx + dy * dy + dw * dw + dh * dh;
            posv = softplusf(-po);
            negc = softplusf(po);    // dense pass counted this cell as negative
            cnt  = 1;
        }

        float fcnt = (float)cnt;
        #pragma unroll
        for (int off = 16; off; off >>= 1) {             // width-32: stay inside the pair
            sq   += __shfl_down(sq,   off, 32);
            posv += __shfl_down(posv, off, 32);
            negc += __shfl_down(negc, off, 32);
            fcnt += __shfl_down(fcnt, off, 32);
        }
        if (l == 0) {
            TgtPart t; t.box = sq; t.pos = posv; t.negc = negc; t.cnt = fcnt;
            tgt_part[pi] = t;
        }
    }
}

// Single block: waves 0-2 sum obj partials per scale; wave 3 reduces the 192
// per-pair target partials (slot/64 == scale by construction); lane 0 combines.
__global__ __launch_bounds__(256) void finalize_kernel(
    const double* __restrict__ obj_part, const TgtPart* __restrict__ tgt_part,
    float* __restrict__ out)
{
    __shared__ double negtot_s[3], box_s[3], pos_s[3], negc_s[3], cnt_s[3];
    const int tid = threadIdx.x;
    const int wave = tid >> 6, lane = tid & 63;

    if (wave < 3) {
        const int start = (wave == 0) ? 0   : (wave == 1 ? NB0       : NB0 + NB1);
        const int end   = (wave == 0) ? NB0 : (wave == 1 ? NB0 + NB1 : NOBJ);
        double sum = 0.0;
        for (int i = start + lane; i < end; i += 64) sum += obj_part[i];
        #pragma unroll
        for (int off = 32; off; off >>= 1) sum += __shfl_down(sum, off);
        if (lane == 0) negtot_s[wave] = sum;
    } else {
        double bx[3], ps[3], ng[3], ct[3];
        #pragma unroll
        for (int q = 0; q < 3; ++q) {
            TgtPart t = tgt_part[lane + 64 * q];   // slot/64 == scale q
            bx[q] = t.box; ps[q] = t.pos; ng[q] = t.negc; ct[q] = t.cnt;
        }
        #pragma unroll
        for (int off = 32; off; off >>= 1) {
            #pragma unroll
            for (int q = 0; q < 3; ++q) {
                bx[q] += __shfl_down(bx[q], off);
                ps[q] += __shfl_down(ps[q], off);
                ng[q] += __shfl_down(ng[q], off);
                ct[q] += __shfl_down(ct[q], off);
            }
        }
        if (lane == 0) {
            #pragma unroll
            for (int q = 0; q < 3; ++q) {
                box_s[q] = bx[q]; pos_s[q] = ps[q]; negc_s[q] = ng[q]; cnt_s[q] = ct[q];
            }
        }
    }
    __syncthreads();
    if (tid == 0) {
        const double cells[3] = {CELLS0, CELLS1, CELLS2};
        double lb = 0.0, lo = 0.0;
        #pragma unroll
        for (int s = 0; s < 3; ++s) {
            double npos = cnt_s[s];
            double nneg = cells[s] - npos;
            lb += box_s[s] / npos;
            lo += pos_s[s] / npos + (negtot_s[s] - negc_s[s]) / nneg;
        }
        out[0] = (float)(0.05 * lb + 1.0 * lo);
    }
}

extern "C" void kernel_launch(void* const* d_in, const int* in_sizes, int n_in,
                              void* d_out, int out_size, void* d_ws, size_t ws_size,
                              hipStream_t stream) {
    const float* p0      = (const float*)d_in[0];
    const float* p1      = (const float*)d_in[1];
    const float* p2      = (const float*)d_in[2];
    const float* boxes   = (const float*)d_in[3];
    // d_in[4] = labels (unused, nc==1)
    const float* anchors = (const float*)d_in[5];

    double*  obj_part = (double*)d_ws;                                  // NOBJ doubles
    TgtPart* tgt_part = (TgtPart*)((char*)d_ws + NOBJ * sizeof(double)); // NPAIR slots
    // every slot is written unconditionally each call -> no zero-init needed

    main_kernel<<<NOBJ + NTGT, 256, 0, stream>>>(p0, p1, p2, boxes, anchors,
                                                 obj_part, tgt_part);
    finalize_kernel<<<1, 256, 0, stream>>>(obj_part, tgt_part, (float*)d_out);
}